// Round 10
// baseline (113.820 us; speedup 1.0000x reference)
//
#include <hip/hip_runtime.h>

#define IDX_BASE 16777216UL   // 4096*64*64
#define LOSS_IDX 17039360UL   // IDX_BASE + 4096*64
#define EPS2 0.02f            // rescue window on (M1 - M2); score err bound ~1e-3

typedef float4 f4;
typedef _Float16 half8 __attribute__((ext_vector_type(8)));
typedef float f32x4 __attribute__((ext_vector_type(4)));

// ---- c2[m][k] = ||codebook[m][k]||^2 (fp32, same table rescue uses) ----
__global__ __launch_bounds__(256) void pq_c2(const float* __restrict__ cb,
                                             float* __restrict__ c2) {
    int m = blockIdx.x, k = threadIdx.x;
    const f4* row = reinterpret_cast<const f4*>(cb + ((size_t)m * 256 + k) * 64);
    float s0 = 0.f, s1 = 0.f;
    #pragma unroll
    for (int i = 0; i < 16; i += 2) {
        f4 a = row[i], b = row[i + 1];
        s0 = fmaf(a.x,a.x,s0); s0 = fmaf(a.y,a.y,s0); s0 = fmaf(a.z,a.z,s0); s0 = fmaf(a.w,a.w,s0);
        s1 = fmaf(b.x,b.x,s1); s1 = fmaf(b.y,b.y,s1); s1 = fmaf(b.z,b.z,s1); s1 = fmaf(b.w,b.w,s1);
    }
    c2[m * 256 + k] = s0 + s1;
}

// ---- precompute code A-fragments (f16 hi/lo), identical conversion to the
//      validated R9 in-register build; layout lane-linear for coalesced loads.
//      unit u = tile*4 + s*2 + hl; fragbuf[m][u][lane] : half8 ----
__global__ __launch_bounds__(256) void pq_frag(const float* __restrict__ cb,
                                               half8* __restrict__ fragbuf) {
    int m = blockIdx.x, tid = threadIdx.x;
    int w = tid >> 6, lane = tid & 63, lh = lane >> 4, l15 = lane & 15;
    const float* cbm = cb + (size_t)m * (256 * 64);
    half8* fbm = fragbuf + (size_t)m * (16 * 4 * 64);
    #pragma unroll
    for (int ti = 0; ti < 4; ++ti) {
        int tile = w * 4 + ti;
        int code = tile * 16 + l15;
        const float* crow = cbm + code * 64 + lh * 8;
        #pragma unroll
        for (int s = 0; s < 2; ++s) {
            f4 a = *reinterpret_cast<const f4*>(crow + s * 32);
            f4 b = *reinterpret_cast<const f4*>(crow + s * 32 + 4);
            float v[8] = {a.x, a.y, a.z, a.w, b.x, b.y, b.z, b.w};
            half8 hi, lo;
            #pragma unroll
            for (int e = 0; e < 8; ++e) {
                _Float16 h = (_Float16)v[e];
                hi[e] = h; lo[e] = (_Float16)(v[e] - (float)h);
            }
            fbm[(tile * 4 + s * 2 + 0) * 64 + lane] = hi;
            fbm[(tile * 4 + s * 2 + 1) * 64 + lane] = lo;
        }
    }
}

// ---- main: NO LDS, NO barriers. Wave = 32 rows (2 row-tiles) of one m,
//      all 256 codes streamed as precomputed A-frags (L2-hot, pipelined). ----
__global__ __launch_bounds__(256, 4) void pq_main(
    const float* __restrict__ z, const float* __restrict__ cb,
    const float* __restrict__ c2ws, const half8* __restrict__ fragbuf,
    float* __restrict__ out, float* __restrict__ partial)
{
    const int tid = threadIdx.x, bx = blockIdx.x;
    const int m = bx >> 5;                       // 32 consecutive blocks share m
    const int w = tid >> 6, lane = tid & 63;
    const int lh = lane >> 4, l15 = lane & 15;
    const int rowbase = (bx & 31) * 128 + w * 32;

    const float* __restrict__ cbm = cb + (size_t)m * (256 * 64);
    const f4* cb4m = reinterpret_cast<const f4*>(cbm);
    const half8* __restrict__ fb = fragbuf + (size_t)m * (16 * 4 * 64);
    const f4* __restrict__ c2t = reinterpret_cast<const f4*>(c2ws + m * 256);

    // ---- resident z B-fragments: 2 row-tiles x {s0,s1} x {hi,lo} (32 VGPR) ----
    half8 zh0[2], zl0[2], zh1[2], zl1[2];        // [h]: s0hi, s0lo, s1hi, s1lo
    #pragma unroll
    for (int h = 0; h < 2; ++h) {
        size_t rh = (size_t)(rowbase + h * 16 + l15);
        const float* zb = z + (rh * 64 + m) * 64 + lh * 8;
        f4 p0 = *reinterpret_cast<const f4*>(zb);
        f4 p1 = *reinterpret_cast<const f4*>(zb + 4);
        f4 p2 = *reinterpret_cast<const f4*>(zb + 32);
        f4 p3 = *reinterpret_cast<const f4*>(zb + 36);
        float v0[8] = {p0.x,p0.y,p0.z,p0.w,p1.x,p1.y,p1.z,p1.w};
        float v1[8] = {p2.x,p2.y,p2.z,p2.w,p3.x,p3.y,p3.z,p3.w};
        #pragma unroll
        for (int e = 0; e < 8; ++e) {
            _Float16 a = (_Float16)v0[e];
            zh0[h][e] = a; zl0[h][e] = (_Float16)(v0[e] - (float)a);
            _Float16 b = (_Float16)v1[e];
            zh1[h][e] = b; zl1[h][e] = (_Float16)(v1[e] - (float)b);
        }
    }

    float m1[2] = {-1e30f, -1e30f}, m2[2] = {-1e30f, -1e30f};
    int   bk[2] = {0, 0};

    // ---- 16 independent code-tiles: 4 coalesced frag loads + c2 + 12 MFMA ----
    #pragma unroll 4
    for (int tile = 0; tile < 16; ++tile) {
        half8 ah0 = fb[(tile * 4 + 0) * 64 + lane];
        half8 al0 = fb[(tile * 4 + 1) * 64 + lane];
        half8 ah1 = fb[(tile * 4 + 2) * 64 + lane];
        half8 al1 = fb[(tile * 4 + 3) * 64 + lane];
        f4 cv = c2t[tile * 4 + lh];
        f32x4 ci; ci[0] = -0.5f*cv.x; ci[1] = -0.5f*cv.y; ci[2] = -0.5f*cv.z; ci[3] = -0.5f*cv.w;
        #pragma unroll
        for (int h = 0; h < 2; ++h) {
            f32x4 acc = ci;
            acc = __builtin_amdgcn_mfma_f32_16x16x32_f16(ah0, h ? zh0[1] : zh0[0], acc, 0, 0, 0);
            acc = __builtin_amdgcn_mfma_f32_16x16x32_f16(ah1, h ? zh1[1] : zh1[0], acc, 0, 0, 0);
            acc = __builtin_amdgcn_mfma_f32_16x16x32_f16(ah0, h ? zl0[1] : zl0[0], acc, 0, 0, 0);
            acc = __builtin_amdgcn_mfma_f32_16x16x32_f16(ah1, h ? zl1[1] : zl1[0], acc, 0, 0, 0);
            acc = __builtin_amdgcn_mfma_f32_16x16x32_f16(al0, h ? zh0[1] : zh0[0], acc, 0, 0, 0);
            acc = __builtin_amdgcn_mfma_f32_16x16x32_f16(al1, h ? zh1[1] : zh1[0], acc, 0, 0, 0);
            #pragma unroll
            for (int r = 0; r < 4; ++r) {
                float v = acc[r];
                int code = tile * 16 + lh * 4 + r;
                m2[h] = fmaxf(m2[h], fminf(v, m1[h]));   // classic top-2 update
                bool gt = v > m1[h];
                m1[h] = gt ? v : m1[h];
                bk[h] = gt ? code : bk[h];
            }
        }
    }

    // ---- per row-tile: merge 4 lane-groups, rescue (rare), epilogue ----
    float lsum = 0.f;
    #pragma unroll
    for (int h = 0; h < 2; ++h) {
        #pragma unroll
        for (int off = 16; off <= 32; off <<= 1) {       // validated R9 merge
            float om1 = __shfl_xor(m1[h], off, 64);
            float om2 = __shfl_xor(m2[h], off, 64);
            int   obk = __shfl_xor(bk[h], off, 64);
            m2[h] = fmaxf(fmaxf(m2[h], om2), fminf(m1[h], om1));
            bool better = (om1 > m1[h]) || (om1 == m1[h] && obk < bk[h]);
            m1[h] = better ? om1 : m1[h];
            bk[h] = better ? obk : bk[h];
        }
        // rescue: exact fp32 rescan (validated R4 arithmetic), z from global
        bool need = (m1[h] - m2[h] < EPS2);
        unsigned mask = (unsigned)(__ballot(need)) & 0xFFFFu;
        while (mask) {
            int row = __builtin_ctz(mask); mask &= mask - 1;
            size_t rg = (size_t)(rowbase + h * 16 + row);
            const f4* zr4 = reinterpret_cast<const f4*>(z + (rg * 64 + m) * 64);
            float bs = -1e30f; int bkx = 0;
            #pragma unroll 1
            for (int j = 0; j < 4; ++j) {
                int k = j * 64 + lane;
                float s = -0.5f * c2ws[m * 256 + k];
                #pragma unroll
                for (int d4 = 0; d4 < 16; ++d4) {
                    f4 c = cb4m[k * 16 + d4];
                    f4 zz = zr4[d4];
                    s = fmaf(zz.x, c.x, s); s = fmaf(zz.y, c.y, s);
                    s = fmaf(zz.z, c.z, s); s = fmaf(zz.w, c.w, s);
                }
                if (s > bs) { bs = s; bkx = k; }
            }
            #pragma unroll
            for (int off = 1; off < 64; off <<= 1) {
                float ov = __shfl_xor(bs, off, 64);
                int   ok = __shfl_xor(bkx, off, 64);
                if (ov > bs || (ov == bs && ok < bkx)) { bs = ov; bkx = ok; }
            }
            bk[h] = (l15 == row) ? bkx : bk[h];
        }
        // epilogue: exact codebook copy + loss (z reconstructed hi+lo)
        size_t rg = (size_t)(rowbase + h * 16 + l15);
        int k = bk[h];
        const f4* qb = reinterpret_cast<const f4*>(cbm + (size_t)k * 64 + lh * 8);
        f4 q0 = qb[0], q1 = qb[1], q2 = qb[8], q3 = qb[9];
        float* ob = out + (rg * 64 + m) * 64 + lh * 8;
        *reinterpret_cast<f4*>(ob)      = q0;
        *reinterpret_cast<f4*>(ob + 4)  = q1;
        *reinterpret_cast<f4*>(ob + 32) = q2;
        *reinterpret_cast<f4*>(ob + 36) = q3;
        float qq0[8] = {q0.x,q0.y,q0.z,q0.w,q1.x,q1.y,q1.z,q1.w};
        float qq1[8] = {q2.x,q2.y,q2.z,q2.w,q3.x,q3.y,q3.z,q3.w};
        #pragma unroll
        for (int e = 0; e < 8; ++e) {
            float zr0 = (float)(h ? zh0[1][e] : zh0[0][e]) + (float)(h ? zl0[1][e] : zl0[0][e]);
            float zr1 = (float)(h ? zh1[1][e] : zh1[0][e]) + (float)(h ? zl1[1][e] : zl1[0][e]);
            float d0 = qq0[e] - zr0, d1 = qq1[e] - zr1;
            lsum = fmaf(d0, d0, lsum); lsum = fmaf(d1, d1, lsum);
        }
        if (lane < 16)
            out[IDX_BASE + rg * 64 + m] = (float)bk[h];
    }

    // ---- per-wave loss partial (no barrier needed) ----
    #pragma unroll
    for (int off = 1; off < 64; off <<= 1) lsum += __shfl_xor(lsum, off, 64);
    if (lane == 0) partial[bx * 4 + w] = lsum;
}

// ---- deterministic final reduction of 8192 wave partials -> q_loss ----
__global__ __launch_bounds__(256) void pq_loss(const float* __restrict__ partial,
                                               float* __restrict__ out)
{
    __shared__ float sW[4];
    float s = 0.f;
    #pragma unroll
    for (int i = 0; i < 32; ++i) s += partial[threadIdx.x + i * 256];
    #pragma unroll
    for (int off = 1; off < 64; off <<= 1) s += __shfl_xor(s, off, 64);
    if ((threadIdx.x & 63) == 0) sW[threadIdx.x >> 6] = s;
    __syncthreads();
    if (threadIdx.x == 0)
        out[LOSS_IDX] = ((sW[0] + sW[1]) + (sW[2] + sW[3])) * (1.25f / 16777216.0f);
}

extern "C" void kernel_launch(void* const* d_in, const int* in_sizes, int n_in,
                              void* d_out, int out_size, void* d_ws, size_t ws_size,
                              hipStream_t stream) {
    const float* zp  = (const float*)d_in[0];
    const float* cbp = (const float*)d_in[1];
    float* outp = (float*)d_out;
    float* c2ws = (float*)d_ws;                        // 16384 floats (64 KB)
    half8* frag = (half8*)((float*)d_ws + 16384);      // 4 MB
    float* part = (float*)d_ws + 16384 + 1048576;      // 8192 floats

    pq_c2  <<<dim3(64),   dim3(256), 0, stream>>>(cbp, c2ws);
    pq_frag<<<dim3(64),   dim3(256), 0, stream>>>(cbp, frag);
    pq_main<<<dim3(2048), dim3(256), 0, stream>>>(zp, cbp, c2ws, frag, outp, part);
    pq_loss<<<dim3(1),    dim3(256), 0, stream>>>(part, outp);
}

// Round 11
// 89.401 us; speedup vs baseline: 1.2731x; 1.2731x over previous
//
#include <hip/hip_runtime.h>

#define IDX_BASE 16777216UL   // 4096*64*64
#define LOSS_IDX 17039360UL   // IDX_BASE + 4096*64
#define EPS2 0.02f            // rescue window on (M1 - M2); score err bound ~1e-3

typedef float4 f4;
typedef _Float16 half8 __attribute__((ext_vector_type(8)));
typedef float f32x4 __attribute__((ext_vector_type(4)));

__device__ __forceinline__ void gload_lds16(const float* g, float* s) {
    __builtin_amdgcn_global_load_lds(
        (const __attribute__((address_space(1))) unsigned int*)g,
        (__attribute__((address_space(3))) unsigned int*)s, 16, 0, 0);
}

// ---- c2[m][k] = ||codebook[m][k]||^2 (fp32, same table rescue uses) ----
__global__ __launch_bounds__(256) void pq_c2(const float* __restrict__ cb,
                                             float* __restrict__ c2) {
    int m = blockIdx.x, k = threadIdx.x;
    const f4* row = reinterpret_cast<const f4*>(cb + ((size_t)m * 256 + k) * 64);
    float s0 = 0.f, s1 = 0.f;
    #pragma unroll
    for (int i = 0; i < 16; i += 2) {
        f4 a = row[i], b = row[i + 1];
        s0 = fmaf(a.x,a.x,s0); s0 = fmaf(a.y,a.y,s0); s0 = fmaf(a.z,a.z,s0); s0 = fmaf(a.w,a.w,s0);
        s1 = fmaf(b.x,b.x,s1); s1 = fmaf(b.y,b.y,s1); s1 = fmaf(b.z,b.z,s1); s1 = fmaf(b.w,b.w,s1);
    }
    c2[m * 256 + k] = s0 + s1;
}

// ---- precompute code A-fragments (f16 hi/lo); validated R10 kernel verbatim.
//      unit u = tile*4 + s*2 + hl; fragbuf[m][u][lane] : half8 ----
__global__ __launch_bounds__(256) void pq_frag(const float* __restrict__ cb,
                                               half8* __restrict__ fragbuf) {
    int m = blockIdx.x, tid = threadIdx.x;
    int w = tid >> 6, lane = tid & 63, lh = lane >> 4, l15 = lane & 15;
    const float* cbm = cb + (size_t)m * (256 * 64);
    half8* fbm = fragbuf + (size_t)m * (16 * 4 * 64);
    #pragma unroll
    for (int ti = 0; ti < 4; ++ti) {
        int tile = w * 4 + ti;
        int code = tile * 16 + l15;
        const float* crow = cbm + code * 64 + lh * 8;
        #pragma unroll
        for (int s = 0; s < 2; ++s) {
            f4 a = *reinterpret_cast<const f4*>(crow + s * 32);
            f4 b = *reinterpret_cast<const f4*>(crow + s * 32 + 4);
            float v[8] = {a.x, a.y, a.z, a.w, b.x, b.y, b.z, b.w};
            half8 hi, lo;
            #pragma unroll
            for (int e = 0; e < 8; ++e) {
                _Float16 h = (_Float16)v[e];
                hi[e] = h; lo[e] = (_Float16)(v[e] - (float)h);
            }
            fbm[(tile * 4 + s * 2 + 0) * 64 + lane] = hi;
            fbm[(tile * 4 + s * 2 + 1) * 64 + lane] = lo;
        }
    }
}

// Block = one m x 128 rows, 4 waves; wave w owns codes w*64..+63 (A-frags loaded
// from fragbuf, no VALU build). z staged fp32 in LDS (swizzled). Row-tiles
// processed in pairs -> 8 independent MFMA chains for latency hiding.
__global__ __launch_bounds__(256, 3) void pq_main(
    const float* __restrict__ z, const float* __restrict__ cb,
    const float* __restrict__ c2ws, const half8* __restrict__ fragbuf,
    float* __restrict__ out, float* __restrict__ partial)
{
    __shared__ f4    sZ4[128 * 16];   // 32 KB; sZ4[r*16+c4] = z[r][(c4^(r&7))*4..]
    __shared__ float sM1[4 * 128];
    __shared__ float sM2[4 * 128];
    __shared__ int   sK [4 * 128];
    __shared__ int   sBest[128];
    __shared__ float sW[4];

    const int tid = threadIdx.x, bx = blockIdx.x;
    // XCD-aware: bx%8 (XCD) picks an m-octet -> per-XCD L2 set = 8 codebooks (1 MB)
    const int m = ((bx & 7) << 3) | ((bx >> 3) & 7);
    const int chunk = bx >> 6;                  // 0..31, rows chunk*128..+127
    const int w = tid >> 6, lane = tid & 63;
    const int lh = lane >> 4, l15 = lane & 15;

    const float* __restrict__ cbm = cb + (size_t)m * (256 * 64);
    const f4* cb4m = reinterpret_cast<const f4*>(cbm);

    // ---- stage z fp32 (pre-swizzled source -> linear LDS), fire DMA first ----
    #pragma unroll
    for (int i = 0; i < 8; ++i) {
        int unit = i * 256 + w * 64 + lane;
        int row = unit >> 4, c4 = unit & 15;
        int c4p = c4 ^ (row & 7);
        const float* src = z + ((size_t)(chunk * 128 + row) * 64 + m) * 64 + c4p * 4;
        gload_lds16(src, (float*)&sZ4[i * 256 + w * 64]);
    }

    // ---- A-fragments: 16 coalesced loads from fragbuf (replaces VALU build) ----
    const half8* __restrict__ fb = fragbuf + (size_t)m * (16 * 4 * 64);
    half8 ah[4][2], al[4][2];
    #pragma unroll
    for (int t = 0; t < 4; ++t) {
        #pragma unroll
        for (int s = 0; s < 2; ++s) {
            ah[t][s] = fb[((w * 4 + t) * 4 + s * 2 + 0) * 64 + lane];
            al[t][s] = fb[((w * 4 + t) * 4 + s * 2 + 1) * 64 + lane];
        }
    }
    // ---- c2 init per lane: k = w*64 + t*16 + lh*4 + r ----
    const f4* __restrict__ c2t = reinterpret_cast<const f4*>(c2ws + m * 256);
    f32x4 c2i[4];
    #pragma unroll
    for (int t = 0; t < 4; ++t) {
        f4 cv = c2t[(w * 4 + t) * 4 + lh];
        c2i[t][0] = -0.5f*cv.x; c2i[t][1] = -0.5f*cv.y;
        c2i[t][2] = -0.5f*cv.z; c2i[t][3] = -0.5f*cv.w;
    }

    __syncthreads();   // z staged

    // ---- main: 4 row-tile PAIRS x {convert x2 + 4x(2x6) MFMA + top-2 x2} ----
    #pragma unroll 1
    for (int rtp = 0; rtp < 4; ++rtp) {
        half8 bh0[2], bl0[2], bh1[2], bl1[2];
        #pragma unroll
        for (int h = 0; h < 2; ++h) {
            const int row = (rtp * 2 + h) * 16 + l15;
            const int swz = row & 7;
            const f4* zr = &sZ4[row * 16];
            const int c0 = lh << 1;
            f4 a0 = zr[(c0)     ^ swz];
            f4 a1 = zr[(c0 + 1) ^ swz];
            f4 a2 = zr[(c0 + 8) ^ swz];
            f4 a3 = zr[(c0 + 9) ^ swz];
            float v0[8] = {a0.x,a0.y,a0.z,a0.w,a1.x,a1.y,a1.z,a1.w};
            float v1[8] = {a2.x,a2.y,a2.z,a2.w,a3.x,a3.y,a3.z,a3.w};
            #pragma unroll
            for (int e = 0; e < 8; ++e) {
                _Float16 h0 = (_Float16)v0[e];
                bh0[h][e] = h0; bl0[h][e] = (_Float16)(v0[e] - (float)h0);
                _Float16 h1 = (_Float16)v1[e];
                bh1[h][e] = h1; bl1[h][e] = (_Float16)(v1[e] - (float)h1);
            }
        }
        float m1[2] = {-1e30f, -1e30f}, m2[2] = {-1e30f, -1e30f};
        int k16[2] = {0, 0};
        #pragma unroll
        for (int t = 0; t < 4; ++t) {
            #pragma unroll
            for (int h = 0; h < 2; ++h) {
                f32x4 acc = c2i[t];
                acc = __builtin_amdgcn_mfma_f32_16x16x32_f16(ah[t][0], bh0[h], acc, 0, 0, 0);
                acc = __builtin_amdgcn_mfma_f32_16x16x32_f16(ah[t][1], bh1[h], acc, 0, 0, 0);
                acc = __builtin_amdgcn_mfma_f32_16x16x32_f16(ah[t][0], bl0[h], acc, 0, 0, 0);
                acc = __builtin_amdgcn_mfma_f32_16x16x32_f16(ah[t][1], bl1[h], acc, 0, 0, 0);
                acc = __builtin_amdgcn_mfma_f32_16x16x32_f16(al[t][0], bh0[h], acc, 0, 0, 0);
                acc = __builtin_amdgcn_mfma_f32_16x16x32_f16(al[t][1], bh1[h], acc, 0, 0, 0);
                #pragma unroll
                for (int r = 0; r < 4; ++r) {
                    float v = acc[r];
                    m2[h] = __builtin_amdgcn_fmed3f(v, m1[h], m2[h]);  // == max(m2,min(v,m1))
                    bool gt = v > m1[h];
                    m1[h]  = gt ? v : m1[h];
                    k16[h] = gt ? (t * 16 + r) : k16[h];
                }
            }
        }
        #pragma unroll
        for (int h = 0; h < 2; ++h) {
            int kw = k16[h] + lh * 4;                  // k within wave's 64 codes
            float a1v = m1[h], a2v = m2[h];
            #pragma unroll
            for (int off = 16; off <= 32; off <<= 1) { // merge 4 lane-groups per row
                float om1 = __shfl_xor(a1v, off, 64);
                float om2 = __shfl_xor(a2v, off, 64);
                int   okw = __shfl_xor(kw, off, 64);
                a2v = fmaxf(fmaxf(a2v, om2), fminf(a1v, om1));
                bool better = (om1 > a1v) || (om1 == a1v && okw < kw);
                a1v = better ? om1 : a1v;
                kw  = better ? okw : kw;
            }
            if (lane < 16) {
                int r2 = (rtp * 2 + h) * 16 + lane;
                sM1[w * 128 + r2] = a1v;
                sM2[w * 128 + r2] = a2v;
                sK [w * 128 + r2] = kw;
            }
        }
    }
    __syncthreads();

    // ---- per-row merge across 4 waves; flag near-ties for exact rescue ----
    if (tid < 128) {
        float M1 = -1e30f, M2 = -1e30f; int K1 = 0;
        #pragma unroll
        for (int w2 = 0; w2 < 4; ++w2) {
            float v1 = sM1[w2 * 128 + tid];
            float v2 = sM2[w2 * 128 + tid];
            int   kk = w2 * 64 + sK[w2 * 128 + tid];
            M2 = fmaxf(fmaxf(M2, v2), fminf(M1, v1));
            bool better = v1 > M1;      // w ascending: ties keep smaller k
            M1 = better ? v1 : M1;
            K1 = better ? kk : K1;
        }
        sBest[tid] = (M1 - M2 < EPS2) ? -1 : K1;
    }
    __syncthreads();

    // ---- rescue (rare): exact fp32 rescan (validated R4 arithmetic) ----
    for (int row = w; row < 128; row += 4) {
        if (sBest[row] >= 0) continue;            // wave-uniform
        int swz = row & 7;
        float bs = -1e30f; int bk = 0;
        #pragma unroll 1
        for (int j = 0; j < 4; ++j) {
            int k = j * 64 + lane;
            float s = -0.5f * c2ws[m * 256 + k];
            #pragma unroll
            for (int d4 = 0; d4 < 16; ++d4) {
                f4 cvv = cb4m[k * 16 + d4];
                f4 zz  = sZ4[row * 16 + (d4 ^ swz)];
                s = fmaf(zz.x, cvv.x, s); s = fmaf(zz.y, cvv.y, s);
                s = fmaf(zz.z, cvv.z, s); s = fmaf(zz.w, cvv.w, s);
            }
            if (s > bs) { bs = s; bk = k; }
        }
        #pragma unroll
        for (int off = 1; off < 64; off <<= 1) {
            float ov = __shfl_xor(bs, off, 64);
            int   ok = __shfl_xor(bk, off, 64);
            if (ov > bs || (ov == bs && ok < bk)) { bs = ov; bk = ok; }
        }
        if (lane == 0) sBest[row] = bk;
    }
    __syncthreads();

    // ---- outputs (R7-validated store pattern: per-lane contiguous 128 B) ----
    float lsum = 0.f;
    {
        int row = tid >> 1, h = tid & 1;
        int k = sBest[row];
        int b = chunk * 128 + row;
        int swz = row & 7;
        const f4* q4 = cb4m + (size_t)k * 16 + h * 8;
        f4*       o4 = reinterpret_cast<f4*>(out + ((size_t)b * 64 + m) * 64) + h * 8;
        float l0 = 0.f, l1 = 0.f;
        #pragma unroll
        for (int c = 0; c < 8; ++c) {
            f4 qv = q4[c];
            f4 zv = sZ4[row * 16 + (((h << 3) + c) ^ swz)];
            o4[c] = qv;
            float d0 = qv.x - zv.x, d1 = qv.y - zv.y, d2 = qv.z - zv.z, d3 = qv.w - zv.w;
            l0 = fmaf(d0, d0, l0); l1 = fmaf(d1, d1, l1);
            l0 = fmaf(d2, d2, l0); l1 = fmaf(d3, d3, l1);
        }
        lsum = l0 + l1;
    }
    if (tid < 128)
        out[IDX_BASE + (size_t)(chunk * 128 + tid) * 64 + m] = (float)sBest[tid];
    #pragma unroll
    for (int off = 1; off < 64; off <<= 1) lsum += __shfl_xor(lsum, off, 64);
    if (lane == 0) sW[w] = lsum;
    __syncthreads();
    if (tid == 0) partial[bx] = (sW[0] + sW[1]) + (sW[2] + sW[3]);
}

// ---- deterministic final reduction of 2048 block partials -> q_loss ----
__global__ __launch_bounds__(256) void pq_loss(const float* __restrict__ partial,
                                               float* __restrict__ out)
{
    __shared__ float sW[4];
    float s = 0.f;
    #pragma unroll
    for (int i = 0; i < 8; ++i) s += partial[threadIdx.x + i * 256];
    #pragma unroll
    for (int off = 1; off < 64; off <<= 1) s += __shfl_xor(s, off, 64);
    if ((threadIdx.x & 63) == 0) sW[threadIdx.x >> 6] = s;
    __syncthreads();
    if (threadIdx.x == 0)
        out[LOSS_IDX] = ((sW[0] + sW[1]) + (sW[2] + sW[3])) * (1.25f / 16777216.0f);
}

extern "C" void kernel_launch(void* const* d_in, const int* in_sizes, int n_in,
                              void* d_out, int out_size, void* d_ws, size_t ws_size,
                              hipStream_t stream) {
    const float* zp  = (const float*)d_in[0];
    const float* cbp = (const float*)d_in[1];
    float* outp = (float*)d_out;
    float* c2ws = (float*)d_ws;                        // 16384 floats (64 KB)
    half8* frag = (half8*)((float*)d_ws + 16384);      // 4 MB
    float* part = (float*)d_ws + 16384 + 1048576;      // 2048 floats

    pq_c2  <<<dim3(64),   dim3(256), 0, stream>>>(cbp, c2ws);
    pq_frag<<<dim3(64),   dim3(256), 0, stream>>>(cbp, frag);
    pq_main<<<dim3(2048), dim3(256), 0, stream>>>(zp, cbp, c2ws, frag, outp, part);
    pq_loss<<<dim3(1),    dim3(256), 0, stream>>>(part, outp);
}